// Round 1
// baseline (140.200 us; speedup 1.0000x reference)
//
#include <hip/hip_runtime.h>

// BallQLoss: B=2, N=8192, K=16, radius=0.5, L1 norm, mean over (B,N,K).
// Strategy: split j-scan 8 ways per query; per-(query,chunk) thread collects
// first <=16 in-ball indices into LDS; per-query merge takes first 16 overall
// in index order (matching pointnet2 ball_query / reference top_k semantics),
// pads short lists with the first found index, accumulates L1 flow loss.

#define NQ   8192
#define NB   2
#define KNN  16
#define R2   0.25f
#define QPB  64            // queries per block
#define NCH  8             // j-chunks (= waves per block)
#define CHUNK (NQ / NCH)   // 1024
#define IDX_STRIDE (NCH * KNN + 1)  // 129 words: 129 % 32 == 1 -> conflict-free

__global__ __launch_bounds__(QPB * NCH)
void BallQLoss_kernel(const float* __restrict__ pc,
                      const float* __restrict__ flow,
                      float* __restrict__ out)
{
    __shared__ int s_idx[QPB][IDX_STRIDE];   // [q][c*16 + t]
    __shared__ int s_cnt[QPB][NCH + 1];      // stride 9 -> conflict-free

    const int tid = threadIdx.x;
    const int q   = tid & (QPB - 1);   // lane id within wave
    const int c   = tid >> 6;          // wave id = j-chunk id
    const int blocksPerB = NQ / QPB;   // 128
    const int b = blockIdx.x / blocksPerB;
    const int i = (blockIdx.x % blocksPerB) * QPB + q;

    const float* __restrict__ pcb = pc   + (size_t)b * NQ * 3;
    const float* __restrict__ flb = flow + (size_t)b * NQ * 3;

    const float qx = pcb[i * 3 + 0];
    const float qy = pcb[i * 3 + 1];
    const float qz = pcb[i * 3 + 2];

    // ---- scan my chunk: first <=16 in-ball indices, in ascending j ----
    int cnt = 0;
    const int jbeg = c * CHUNK;
    const int jend = jbeg + CHUNK;
#pragma unroll 4
    for (int j = jbeg; j < jend; ++j) {
        // wave-uniform address: all 64 lanes read the same point (broadcast)
        const float px = pcb[j * 3 + 0];
        const float py = pcb[j * 3 + 1];
        const float pz = pcb[j * 3 + 2];
        const float dx = qx - px, dy = qy - py, dz = qz - pz;
        const float d2 = dx * dx + dy * dy + dz * dz;
        if (d2 < R2 && cnt < KNN) {
            s_idx[q][c * KNN + cnt] = j;
            ++cnt;
        }
    }
    s_cnt[q][c] = cnt;
    __syncthreads();

    // ---- merge (wave 0 only): first 16 across chunks in order + loss ----
    if (c == 0) {
        const float fx = flb[i * 3 + 0];
        const float fy = flb[i * 3 + 1];
        const float fz = flb[i * 3 + 2];

        float loss = 0.0f;
        int remaining = KNN;
        int first = -1;
        for (int c2 = 0; c2 < NCH; ++c2) {
            const int f    = s_cnt[q][c2];
            const int take = f < remaining ? f : remaining;
            for (int t = 0; t < take; ++t) {
                const int jj = s_idx[q][c2 * KNN + t];
                if (first < 0) first = jj;
                const float gx = flb[jj * 3 + 0];
                const float gy = flb[jj * 3 + 1];
                const float gz = flb[jj * 3 + 2];
                loss += fabsf(fx - gx) + fabsf(fy - gy) + fabsf(fz - gz);
            }
            remaining -= take;
        }
        if (remaining > 0) {
            // pad empty slots with the first found neighbor (self always in-ball)
            const float gx = flb[first * 3 + 0];
            const float gy = flb[first * 3 + 1];
            const float gz = flb[first * 3 + 2];
            loss += (float)remaining *
                    (fabsf(fx - gx) + fabsf(fy - gy) + fabsf(fz - gz));
        }

        // wave-level reduction over the 64 query lanes
        for (int off = 32; off > 0; off >>= 1)
            loss += __shfl_down(loss, off, 64);
        if (q == 0)
            atomicAdd(out, loss * (1.0f / ((float)NB * NQ * KNN)));
    }
}

extern "C" void kernel_launch(void* const* d_in, const int* in_sizes, int n_in,
                              void* d_out, int out_size, void* d_ws, size_t ws_size,
                              hipStream_t stream)
{
    (void)in_sizes; (void)n_in; (void)d_ws; (void)ws_size; (void)out_size;
    const float* pc   = (const float*)d_in[0];
    const float* flow = (const float*)d_in[1];
    float* out = (float*)d_out;

    hipMemsetAsync(out, 0, sizeof(float), stream);
    const int grid = NB * NQ / QPB;  // 256 blocks x 512 threads
    BallQLoss_kernel<<<grid, QPB * NCH, 0, stream>>>(pc, flow, out);
}

// Round 2
// 69.913 us; speedup vs baseline: 2.0053x; 2.0053x over previous
//
#include <hip/hip_runtime.h>

// BallQLoss: B=2, N=8192, K=16, radius=0.5, L1 norm, mean over (B,N,K).
// v2: wave = (64-query group, 512-point chunk). Each lane owns one query.
// Points are loaded coalesced (one per lane per 64-batch) then broadcast via
// v_readlane (constant lane index -> SGPR operand), making the inner loop
// pure VALU. Hits recorded as a 64-bit mask per batch, extracted via ctz.
// Merge wave takes first 16 across chunks in index order (pointnet2
// semantics), pads with first found neighbor, accumulates L1 flow loss.

#define NQ   8192
#define NB   2
#define KNN  16
#define R2   0.25f
#define QPB  64                      // queries per block (= lanes per wave)
#define NCH  16                      // chunks = waves per block
#define CHUNK (NQ / NCH)             // 512 points per wave
#define IDX_STRIDE (NCH * KNN + 1)   // 257 ints: 257 % 32 == 1 -> conflict-free

__global__ __launch_bounds__(QPB * NCH)
void BallQLoss_kernel(const float* __restrict__ pc,
                      const float* __restrict__ flow,
                      float* __restrict__ out)
{
    __shared__ int s_idx[QPB][IDX_STRIDE];   // [q][c*16 + t]
    __shared__ int s_cnt[QPB][NCH + 1];      // stride 17 -> conflict-free

    const int tid = threadIdx.x;
    const int q   = tid & (QPB - 1);   // lane id = query slot
    const int c   = tid >> 6;          // wave id = chunk id
    const int blocksPerB = NQ / QPB;   // 128
    const int b = blockIdx.x / blocksPerB;
    const int i = (blockIdx.x % blocksPerB) * QPB + q;

    const float* __restrict__ pcb = pc   + (size_t)b * NQ * 3;
    const float* __restrict__ flb = flow + (size_t)b * NQ * 3;

    const float qx = pcb[i * 3 + 0];
    const float qy = pcb[i * 3 + 1];
    const float qz = pcb[i * 3 + 2];

    int cnt = 0;
    const int jbeg = c * CHUNK;

    for (int t0 = 0; t0 < CHUNK; t0 += 64) {
        // coalesced: lane q loads point (jbeg + t0 + q)
        const int jl = jbeg + t0 + q;
        const float px = pcb[jl * 3 + 0];
        const float py = pcb[jl * 3 + 1];
        const float pz = pcb[jl * 3 + 2];

        unsigned int mlo = 0u, mhi = 0u;
#pragma unroll
        for (int t = 0; t < 64; ++t) {
            // broadcast lane t's point into SGPRs (free VALU operands)
            const float sx = __uint_as_float(__builtin_amdgcn_readlane(__float_as_uint(px), t));
            const float sy = __uint_as_float(__builtin_amdgcn_readlane(__float_as_uint(py), t));
            const float sz = __uint_as_float(__builtin_amdgcn_readlane(__float_as_uint(pz), t));
            const float dx = qx - sx, dy = qy - sy, dz = qz - sz;
            const float d2 = dx * dx + dy * dy + dz * dz;
            const unsigned int hit = (d2 < R2) ? 1u : 0u;
            if (t < 32) mlo |= hit << t;
            else        mhi |= hit << (t - 32);
        }

        unsigned long long m = ((unsigned long long)mhi << 32) | mlo;
        while (m && cnt < KNN) {
            const int bpos = __builtin_ctzll(m);
            s_idx[q][c * KNN + cnt] = jbeg + t0 + bpos;
            ++cnt;
            m &= m - 1;
        }
    }
    s_cnt[q][c] = cnt;
    __syncthreads();

    // ---- merge (wave 0): first 16 across chunks in order + L1 loss ----
    if (c == 0) {
        const float fx = flb[i * 3 + 0];
        const float fy = flb[i * 3 + 1];
        const float fz = flb[i * 3 + 2];

        float loss = 0.0f;
        int remaining = KNN;
        int first = -1;
        for (int c2 = 0; c2 < NCH; ++c2) {
            const int f    = s_cnt[q][c2];
            const int take = f < remaining ? f : remaining;
            for (int t = 0; t < take; ++t) {
                const int jj = s_idx[q][c2 * KNN + t];
                if (first < 0) first = jj;
                const float gx = flb[jj * 3 + 0];
                const float gy = flb[jj * 3 + 1];
                const float gz = flb[jj * 3 + 2];
                loss += fabsf(fx - gx) + fabsf(fy - gy) + fabsf(fz - gz);
            }
            remaining -= take;
        }
        if (remaining > 0) {
            // pad empty slots with first found neighbor (self always in-ball)
            const float gx = flb[first * 3 + 0];
            const float gy = flb[first * 3 + 1];
            const float gz = flb[first * 3 + 2];
            loss += (float)remaining *
                    (fabsf(fx - gx) + fabsf(fy - gy) + fabsf(fz - gz));
        }

        for (int off = 32; off > 0; off >>= 1)
            loss += __shfl_down(loss, off, 64);
        if (q == 0)
            atomicAdd(out, loss * (1.0f / ((float)NB * NQ * KNN)));
    }
}

extern "C" void kernel_launch(void* const* d_in, const int* in_sizes, int n_in,
                              void* d_out, int out_size, void* d_ws, size_t ws_size,
                              hipStream_t stream)
{
    (void)in_sizes; (void)n_in; (void)d_ws; (void)ws_size; (void)out_size;
    const float* pc   = (const float*)d_in[0];
    const float* flow = (const float*)d_in[1];
    float* out = (float*)d_out;

    hipMemsetAsync(out, 0, sizeof(float), stream);
    const int grid = NB * NQ / QPB;  // 256 blocks x 1024 threads
    BallQLoss_kernel<<<grid, QPB * NCH, 0, stream>>>(pc, flow, out);
}

// Round 3
// 58.996 us; speedup vs baseline: 2.3765x; 1.1851x over previous
//
#include <hip/hip_runtime.h>
#include <hip/hip_fp16.h>

// BallQLoss: B=2, N=8192, K=16, radius=0.5, L1 norm, mean over (B,N,K).
// v3: two-kernel. K1 (scan): wave = 64 queries x 256-candidate chunk, j-range
// split 4x across blocks (8192 waves -> 8/SIMD capacity). Candidates packed
// as f16 pairs; distance via v_pk ops (2 pts/instr); hit bit taken from the
// sign bit of d2-R^2 and accumulated with lshl_or into even/odd masks.
// Per-chunk first-16 lists merged intra-block, quarter lists -> d_ws (u16).
// K2 (merge+loss): one lane per query merges 4 ordered quarter lists, takes
// first 16 in index order (pointnet2 semantics), pads with first neighbor,
// gathers flows, L1-reduces, atomically accumulates the mean.

#define NQ   8192
#define NB   2
#define KNN  16
#define QPB  64
#define WAVES 8                        // waves per K1 block
#define GROUPS (NB * NQ / QPB)         // 256
#define NBQ (NB * NQ)                  // 16384 total queries
#define IDX_STRIDE (WAVES * KNN + 1)   // 129 -> conflict-free

template<int JS>
__global__ __launch_bounds__(QPB * WAVES, 6)
void ballq_scan(const float* __restrict__ pc,
                unsigned short* __restrict__ wsIdx,
                int* __restrict__ wsCnt)
{
    __shared__ int s_idx[QPB][IDX_STRIDE];
    __shared__ int s_cnt[QPB][WAVES + 1];

    const int tid = threadIdx.x;
    const int q   = tid & 63;          // lane = query slot
    const int c   = tid >> 6;          // wave = sub-chunk
    const int s   = blockIdx.x % JS;   // j-split slice
    const int g   = blockIdx.x / JS;   // query group 0..255
    const int b   = g >> 7;            // batch
    const int i   = (g & 127) * QPB + q;

    const float* __restrict__ pcb = pc + (size_t)b * NQ * 3;

    const float qx = pcb[i * 3 + 0];
    const float qy = pcb[i * 3 + 1];
    const float qz = pcb[i * 3 + 2];
    const unsigned qhx = __half_as_ushort(__float2half(qx));
    const unsigned qhy = __half_as_ushort(__float2half(qy));
    const unsigned qhz = __half_as_ushort(__float2half(qz));
    const __half2 qpx = __builtin_bit_cast(__half2, qhx * 0x10001u);
    const __half2 qpy = __builtin_bit_cast(__half2, qhy * 0x10001u);
    const __half2 qpz = __builtin_bit_cast(__half2, qhz * 0x10001u);
    const __half2 r2pk = __floats2half2_rn(0.25f, 0.25f);

    constexpr int CHUNK = NQ / (JS * WAVES);
    const int jbase0 = s * (NQ / JS) + c * CHUNK;

    int cnt = 0;
    for (int t0 = 0; t0 < CHUNK; t0 += 64) {
        const int base = jbase0 + t0;
        const int jl   = base + q;
        // coalesced candidate load, convert to f16 bits
        const unsigned hx = __half_as_ushort(__float2half(pcb[jl * 3 + 0]));
        const unsigned hy = __half_as_ushort(__float2half(pcb[jl * 3 + 1]));
        const unsigned hz = __half_as_ushort(__float2half(pcb[jl * 3 + 2]));
        // pack (even-j, odd-j) pairs: both lanes of a pair hold the same word
        const unsigned ox = (unsigned)__shfl_xor((int)hx, 1, 64);
        const unsigned oy = (unsigned)__shfl_xor((int)hy, 1, 64);
        const unsigned oz = (unsigned)__shfl_xor((int)hz, 1, 64);
        const unsigned wx = (q & 1) ? (ox | (hx << 16)) : (hx | (ox << 16));
        const unsigned wy = (q & 1) ? (oy | (hy << 16)) : (hy | (oy << 16));
        const unsigned wz = (q & 1) ? (oz | (hz << 16)) : (hz | (oz << 16));

        unsigned m_ev = 0u, m_od = 0u;
#pragma unroll
        for (int p = 0; p < 32; ++p) {
            const unsigned sx = (unsigned)__builtin_amdgcn_readlane((int)wx, 2 * p);
            const unsigned sy = (unsigned)__builtin_amdgcn_readlane((int)wy, 2 * p);
            const unsigned sz = (unsigned)__builtin_amdgcn_readlane((int)wz, 2 * p);
            const __half2 dx = __hsub2(qpx, __builtin_bit_cast(__half2, sx));
            const __half2 dy = __hsub2(qpy, __builtin_bit_cast(__half2, sy));
            const __half2 dz = __hsub2(qpz, __builtin_bit_cast(__half2, sz));
            const __half2 d2 = __hfma2(dx, dx, __hfma2(dy, dy, __hmul2(dz, dz)));
            // hit iff d2 < R2 iff (d2 - R2) < 0 -> sign bit set (d2==R2 -> +0, no hit)
            const unsigned su = __builtin_bit_cast(unsigned, __hsub2(d2, r2pk));
            m_ev |= ((su >> 15) & 1u) << p;   // even candidate (base+2p)
            m_od |= (su >> 31) << p;          // odd candidate (base+2p+1)
        }

        // extract hits in ascending j until 16 found
        while ((m_ev | m_od) && cnt < KNN) {
            const unsigned pe = m_ev ? (unsigned)__builtin_ctz(m_ev) : 99u;
            const unsigned po = m_od ? (unsigned)__builtin_ctz(m_od) : 99u;
            int j;
            if (pe <= po) { j = base + 2 * (int)pe;     m_ev &= m_ev - 1u; }
            else          { j = base + 2 * (int)po + 1; m_od &= m_od - 1u; }
            s_idx[q][c * KNN + cnt] = j;
            ++cnt;
        }
    }
    s_cnt[q][c] = cnt;
    __syncthreads();

    // intra-block merge: first <=16 over this block's j-slice, in order
    if (c == 0) {
        const int row = s * NBQ + g * QPB + q;
        unsigned short* __restrict__ rp = wsIdx + (size_t)row * KNN;
        int outc = 0;
        for (int c2 = 0; c2 < WAVES && outc < KNN; ++c2) {
            const int f = s_cnt[q][c2];
            const int take = f < (KNN - outc) ? f : (KNN - outc);
            for (int t = 0; t < take; ++t)
                rp[outc++] = (unsigned short)s_idx[q][c2 * KNN + t];
        }
        wsCnt[row] = outc;
    }
}

__global__ __launch_bounds__(256)
void ballq_loss(const float* __restrict__ flow,
                const unsigned short* __restrict__ wsIdx,
                const int* __restrict__ wsCnt,
                float* __restrict__ out, int JS)
{
    const int i  = blockIdx.x * 256 + threadIdx.x;  // global query 0..16383
    const int b  = i >> 13;
    const int iq = i & (NQ - 1);
    const float* __restrict__ flb = flow + (size_t)b * NQ * 3;

    const float fx = flb[iq * 3 + 0];
    const float fy = flb[iq * 3 + 1];
    const float fz = flb[iq * 3 + 2];

    float loss = 0.0f;
    int rem = KNN;
    int first = -1;
    for (int s = 0; s < JS && rem > 0; ++s) {
        const int cs = wsCnt[s * NBQ + i];
        const unsigned short* __restrict__ rp = wsIdx + ((size_t)s * NBQ + i) * KNN;
        const int take = cs < rem ? cs : rem;
        for (int t = 0; t < take; ++t) {
            const int j = rp[t];
            if (first < 0) first = j;
            loss += fabsf(fx - flb[j * 3 + 0]) +
                    fabsf(fy - flb[j * 3 + 1]) +
                    fabsf(fz - flb[j * 3 + 2]);
        }
        rem -= take;
    }
    if (rem > 0) {
        // pad with first (smallest-index) neighbor; self is always in-ball
        loss += (float)rem * (fabsf(fx - flb[first * 3 + 0]) +
                              fabsf(fy - flb[first * 3 + 1]) +
                              fabsf(fz - flb[first * 3 + 2]));
    }

    for (int off = 32; off > 0; off >>= 1)
        loss += __shfl_down(loss, off, 64);
    __shared__ float sred[4];
    if ((threadIdx.x & 63) == 0) sred[threadIdx.x >> 6] = loss;
    __syncthreads();
    if (threadIdx.x == 0) {
        const float t = sred[0] + sred[1] + sred[2] + sred[3];
        atomicAdd(out, t * (1.0f / ((float)NB * NQ * KNN)));
    }
}

extern "C" void kernel_launch(void* const* d_in, const int* in_sizes, int n_in,
                              void* d_out, int out_size, void* d_ws, size_t ws_size,
                              hipStream_t stream)
{
    (void)in_sizes; (void)n_in; (void)out_size;
    const float* pc   = (const float*)d_in[0];
    const float* flow = (const float*)d_in[1];
    float* out = (float*)d_out;

    hipMemsetAsync(out, 0, sizeof(float), stream);

    // pick j-split by available workspace: JS * 16384 * (16*2 + 4) bytes
    const size_t per = (size_t)NBQ * (KNN * 2 + 4);
    int JS = (ws_size >= 4 * per) ? 4 : (ws_size >= 2 * per) ? 2 : 1;

    unsigned short* wsIdx = (unsigned short*)d_ws;
    int* wsCnt = (int*)((char*)d_ws + (size_t)JS * NBQ * KNN * 2);

    if (JS == 4)
        ballq_scan<4><<<GROUPS * 4, QPB * WAVES, 0, stream>>>(pc, wsIdx, wsCnt);
    else if (JS == 2)
        ballq_scan<2><<<GROUPS * 2, QPB * WAVES, 0, stream>>>(pc, wsIdx, wsCnt);
    else
        ballq_scan<1><<<GROUPS * 1, QPB * WAVES, 0, stream>>>(pc, wsIdx, wsCnt);

    ballq_loss<<<NBQ / 256, 256, 0, stream>>>(flow, wsIdx, wsCnt, out, JS);
}

// Round 4
// 58.116 us; speedup vs baseline: 2.4124x; 1.0151x over previous
//
#include <hip/hip_runtime.h>
#include <hip/hip_fp16.h>

// BallQLoss: B=2, N=8192, K=16, radius=0.5, L1 norm, mean over (B,N,K).
// v4: K1 scan: wave = 64 queries x 128-candidate batch (lane owns a candidate
// PAIR loaded as 3x float2, packed to f16x2 via v_cvt_pkrtz). Pair words are
// broadcast via readlane; packed distance (v_pk f16); hit bits = sign of
// d2-R^2 accumulated 2-ops/pair into 4 group masks, decoded to even/odd
// 64-bit streams, extracted in ascending j (pointnet2 first-K semantics).
// j-range split JS x across blocks; slice lists (u16) + counts (u8) -> d_ws.
// K2: 16 lanes per query, one per k-slot; slot->slice decode; padded slots
// use slot 0 (first neighbor); gather flows, L1, block-reduce, atomicAdd.

#define NQ   8192
#define NB   2
#define KNN  16
#define QPB  64
#define WAVES 8
#define GROUPS (NB * NQ / QPB)         // 256
#define NBQ (NB * NQ)                  // 16384
#define IDX_STRIDE (WAVES * KNN + 1)   // 129 -> conflict-free

typedef _Float16 f16x2_t __attribute__((ext_vector_type(2)));

static __device__ __forceinline__ unsigned pkrtz_u(float a, float b) {
    return __builtin_bit_cast(unsigned, __builtin_amdgcn_cvt_pkrtz(a, b));
}
static __device__ __forceinline__ __half2 u_as_h2(unsigned u) {
    return __builtin_bit_cast(__half2, u);
}

template<int JS>
__global__ __launch_bounds__(QPB * WAVES, 8)
void ballq_scan(const float* __restrict__ pc,
                unsigned short* __restrict__ wsIdx,
                unsigned char* __restrict__ wsCnt)
{
    __shared__ int s_idx[QPB][IDX_STRIDE];
    __shared__ int s_cnt[QPB][WAVES + 1];

    const int tid = threadIdx.x;
    const int q   = tid & 63;          // lane = query slot
    const int c   = tid >> 6;          // wave = sub-chunk
    const int s   = blockIdx.x % JS;   // j slice
    const int g   = blockIdx.x / JS;   // query group 0..255
    const int b   = g >> 7;
    const int i   = (g & 127) * QPB + q;

    const float* __restrict__ pcb = pc + (size_t)b * NQ * 3;
    const float2* __restrict__ pairs = (const float2*)pcb;

    const float qx = pcb[i * 3 + 0];
    const float qy = pcb[i * 3 + 1];
    const float qz = pcb[i * 3 + 2];
    const __half2 qpx = u_as_h2(pkrtz_u(qx, qx));
    const __half2 qpy = u_as_h2(pkrtz_u(qy, qy));
    const __half2 qpz = u_as_h2(pkrtz_u(qz, qz));
    const __half2 r2pk = u_as_h2(0x34003400u);   // (0.25, 0.25)

    constexpr int CHUNK = NQ / (JS * WAVES);
    const int jbase0 = s * (NQ / JS) + c * CHUNK;

    // lane owns pair (base + 2q, base + 2q + 1): floats [3*base + 6q .. +5]
    size_t fb = (size_t)jbase0 * 3 / 2 + 3 * q;  // float2 index
    float2 v0 = pairs[fb + 0];   // (x_e, y_e)
    float2 v1 = pairs[fb + 1];   // (z_e, x_o)
    float2 v2 = pairs[fb + 2];   // (y_o, z_o)

    int cnt = 0;
    for (int t0 = 0; t0 < CHUNK; t0 += 128) {
        const int base = jbase0 + t0;
        const unsigned uwx = pkrtz_u(v0.x, v1.y);
        const unsigned uwy = pkrtz_u(v0.y, v2.x);
        const unsigned uwz = pkrtz_u(v1.x, v2.y);
        if (t0 + 128 < CHUNK) {          // prefetch next batch
            fb += 192;                   // 128*3/2
            v0 = pairs[fb + 0]; v1 = pairs[fb + 1]; v2 = pairs[fb + 2];
        }

        unsigned m0 = 0u, m1 = 0u, m2 = 0u, m3 = 0u;
#pragma unroll
        for (int p = 0; p < 64; ++p) {
            const unsigned sx = (unsigned)__builtin_amdgcn_readlane((int)uwx, p);
            const unsigned sy = (unsigned)__builtin_amdgcn_readlane((int)uwy, p);
            const unsigned sz = (unsigned)__builtin_amdgcn_readlane((int)uwz, p);
            const __half2 dx = __hsub2(qpx, u_as_h2(sx));
            const __half2 dy = __hsub2(qpy, u_as_h2(sy));
            const __half2 dz = __hsub2(qpz, u_as_h2(sz));
            const __half2 d2 = __hfma2(dx, dx, __hfma2(dy, dy, __hmul2(dz, dz)));
            // hit iff d2 < 0.25 <=> sign(d2 - 0.25); lo half bit15 = even cand,
            // hi half bit31 = odd cand
            const unsigned su =
                __builtin_bit_cast(unsigned, __hsub2(d2, r2pk)) & 0x80008000u;
            if      (p < 16) m0 = su | (m0 >> 1);
            else if (p < 32) m1 = su | (m1 >> 1);
            else if (p < 48) m2 = su | (m2 >> 1);
            else             m3 = su | (m3 >> 1);
        }
        // group k: bit b(<16) = even cand of pair 16k+b; bit 16+b = odd cand
        unsigned long long ev =
              (unsigned long long)(m0 & 0xFFFFu)
            | ((unsigned long long)(m1 & 0xFFFFu) << 16)
            | ((unsigned long long)(m2 & 0xFFFFu) << 32)
            | ((unsigned long long)(m3 & 0xFFFFu) << 48);
        unsigned long long od =
              (unsigned long long)(m0 >> 16)
            | ((unsigned long long)(m1 >> 16) << 16)
            | ((unsigned long long)(m2 >> 16) << 32)
            | ((unsigned long long)(m3 >> 16) << 48);

        while ((ev | od) && cnt < KNN) {
            const int pe = ev ? __builtin_ctzll(ev) : 127;
            const int po = od ? __builtin_ctzll(od) : 127;
            int j;
            if (pe <= po) { j = base + 2 * pe;     ev &= ev - 1; }
            else          { j = base + 2 * po + 1; od &= od - 1; }
            s_idx[q][c * KNN + cnt] = j;
            ++cnt;
        }
    }
    s_cnt[q][c] = cnt;
    __syncthreads();

    // intra-block ordered merge: first <=16 over this block's j-slice
    if (c == 0) {
        const int qid = g * QPB + q;   // 0..16383
        unsigned short* __restrict__ rp = wsIdx + ((size_t)s * NBQ + qid) * KNN;
        int outc = 0;
        for (int c2 = 0; c2 < WAVES && outc < KNN; ++c2) {
            const int f = s_cnt[q][c2];
            const int take = f < (KNN - outc) ? f : (KNN - outc);
            for (int t = 0; t < take; ++t)
                rp[outc++] = (unsigned short)s_idx[q][c2 * KNN + t];
        }
        wsCnt[qid * 4 + s] = (unsigned char)outc;
    }
}

template<int JS>
__global__ __launch_bounds__(256)
void ballq_loss(const float* __restrict__ flow,
                const unsigned short* __restrict__ wsIdx,
                const unsigned char* __restrict__ wsCnt,
                float* __restrict__ out)
{
    const int tid = blockIdx.x * 256 + threadIdx.x;
    const int qid = tid >> 4;          // one query per 16 lanes
    const int t   = tid & 15;          // k-slot
    const int b   = qid >> 13;
    const int iq  = qid & (NQ - 1);
    const float* __restrict__ flb = flow + (size_t)b * NQ * 3;

    const unsigned cw = *(const unsigned*)(wsCnt + qid * 4);
    const int b0 = cw & 0xFF;
    const int b1 = (JS > 1) ? ((cw >> 8)  & 0xFF) : 0;
    const int b2 = (JS > 2) ? ((cw >> 16) & 0xFF) : 0;
    const int b3 = (JS > 3) ? ((cw >> 24) & 0xFF) : 0;
    const int c1 = b0, c2c = b0 + b1, c3 = b0 + b1 + b2;
    int tot = b0 + b1 + b2 + b3;
    if (tot > KNN) tot = KNN;
    // tot >= 1 always: self is in-ball (d2 == 0)

    const int seff = (t < tot) ? t : 0;   // padded slots -> slot 0 (first nb)
    const int sl   = (seff >= c1) + (seff >= c2c) + (seff >= c3);
    const int cum  = (sl == 0) ? 0 : (sl == 1) ? c1 : (sl == 2) ? c2c : c3;
    const int j    = wsIdx[((size_t)sl * NBQ + qid) * KNN + (seff - cum)];

    const float fx = flb[iq * 3 + 0];
    const float fy = flb[iq * 3 + 1];
    const float fz = flb[iq * 3 + 2];
    float l = fabsf(fx - flb[j * 3 + 0]) +
              fabsf(fy - flb[j * 3 + 1]) +
              fabsf(fz - flb[j * 3 + 2]);

    for (int o = 32; o > 0; o >>= 1)
        l += __shfl_down(l, o, 64);
    __shared__ float sred[4];
    if ((threadIdx.x & 63) == 0) sred[threadIdx.x >> 6] = l;
    __syncthreads();
    if (threadIdx.x == 0)
        atomicAdd(out, (sred[0] + sred[1] + sred[2] + sred[3]) *
                           (1.0f / ((float)NB * NQ * KNN)));
}

extern "C" void kernel_launch(void* const* d_in, const int* in_sizes, int n_in,
                              void* d_out, int out_size, void* d_ws, size_t ws_size,
                              hipStream_t stream)
{
    (void)in_sizes; (void)n_in; (void)out_size;
    const float* pc   = (const float*)d_in[0];
    const float* flow = (const float*)d_in[1];
    float* out = (float*)d_out;

    hipMemsetAsync(out, 0, sizeof(float), stream);

    const size_t idxB = (size_t)NBQ * KNN * 2;   // 512 KB per slice
    const size_t cntB = (size_t)NBQ * 4;
    const int JS = (ws_size >= 4 * idxB + cntB) ? 4
                 : (ws_size >= 2 * idxB + cntB) ? 2 : 1;

    unsigned short* wsIdx = (unsigned short*)d_ws;

    if (JS == 4) {
        unsigned char* wsCnt = (unsigned char*)d_ws + 4 * idxB;
        ballq_scan<4><<<GROUPS * 4, QPB * WAVES, 0, stream>>>(pc, wsIdx, wsCnt);
        ballq_loss<4><<<NBQ * 16 / 256, 256, 0, stream>>>(flow, wsIdx, wsCnt, out);
    } else if (JS == 2) {
        unsigned char* wsCnt = (unsigned char*)d_ws + 2 * idxB;
        ballq_scan<2><<<GROUPS * 2, QPB * WAVES, 0, stream>>>(pc, wsIdx, wsCnt);
        ballq_loss<2><<<NBQ * 16 / 256, 256, 0, stream>>>(flow, wsIdx, wsCnt, out);
    } else {
        unsigned char* wsCnt = (unsigned char*)d_ws + 1 * idxB;
        ballq_scan<1><<<GROUPS * 1, QPB * WAVES, 0, stream>>>(pc, wsIdx, wsCnt);
        ballq_loss<1><<<NBQ * 16 / 256, 256, 0, stream>>>(flow, wsIdx, wsCnt, out);
    }
}